// Round 1
// baseline (766.245 us; speedup 1.0000x reference)
//
#include <hip/hip_runtime.h>

// GCN encoder: 2x GCNConv(+ReLU) + Linear(+ReLU).
// Baseline: atomic-scatter aggregation, fp32 end-to-end.

__global__ void k_init_deg(float* __restrict__ deg, int n) {
    int i = blockIdx.x * blockDim.x + threadIdx.x;
    if (i < n) deg[i] = 1.0f;  // self-loop
}

__global__ void k_count_deg(const int* __restrict__ dst, float* __restrict__ deg, int E) {
    int e = blockIdx.x * blockDim.x + threadIdx.x;
    if (e < E) atomicAdd(&deg[dst[e]], 1.0f);
}

__global__ void k_dinv(float* __restrict__ deg, int n) {
    int i = blockIdx.x * blockDim.x + threadIdx.x;
    if (i < n) deg[i] = rsqrtf(deg[i]);  // deg >= 1 always (self-loops)
}

// h1[n][c] = sum_k x[n][k] * W1[k][c];  agg1 init = self-loop term h1*dinv^2
__global__ void k_lin1(const float* __restrict__ x, const float* __restrict__ W1,
                       const float* __restrict__ dinv, float* __restrict__ h1,
                       float* __restrict__ agg1, int n) {
    int t = blockIdx.x * blockDim.x + threadIdx.x;
    if (t >= n * 64) return;
    int node = t >> 6, c = t & 63;
    float4 xv = ((const float4*)x)[node];
    float v = xv.x * W1[c] + xv.y * W1[64 + c] + xv.z * W1[128 + c] + xv.w * W1[192 + c];
    h1[t] = v;
    float di = dinv[node];
    agg1[t] = v * di * di;
}

// one wave per edge, lane = channel (64)
__global__ void k_scatter1(const int* __restrict__ src, const int* __restrict__ dst,
                           const float* __restrict__ dinv, const float* __restrict__ h1,
                           float* __restrict__ agg1, int E) {
    int wid = (int)((blockIdx.x * (unsigned)blockDim.x + threadIdx.x) >> 6);
    int lane = threadIdx.x & 63;
    if (wid >= E) return;
    int s = src[wid], d = dst[wid];
    float norm = dinv[s] * dinv[d];
    atomicAdd(&agg1[(size_t)d * 64 + lane], h1[(size_t)s * 64 + lane] * norm);
}

// relu(agg1 + b1) @ W2 -> h2;  agg2 init = self-loop term h2*dinv^2
__global__ void k_lin2(const float* __restrict__ agg1, const float* __restrict__ b1,
                       const float* __restrict__ W2, const float* __restrict__ dinv,
                       float* __restrict__ h2, float* __restrict__ agg2, int n) {
    int t = blockIdx.x * blockDim.x + threadIdx.x;
    if (t >= n * 32) return;
    int node = t >> 5, c = t & 31;
    const float* row = agg1 + (size_t)node * 64;
    float acc = 0.0f;
#pragma unroll
    for (int j = 0; j < 64; ++j) {
        float hv = fmaxf(row[j] + b1[j], 0.0f);
        acc = fmaf(hv, W2[j * 32 + c], acc);
    }
    h2[t] = acc;
    float di = dinv[node];
    agg2[t] = acc * di * di;
}

// half-wave per edge, lane%32 = channel
__global__ void k_scatter2(const int* __restrict__ src, const int* __restrict__ dst,
                           const float* __restrict__ dinv, const float* __restrict__ h2,
                           float* __restrict__ agg2, int E) {
    unsigned t = blockIdx.x * (unsigned)blockDim.x + threadIdx.x;
    int e = (int)(t >> 5);
    int c = (int)(t & 31);
    if (e >= E) return;
    int s = src[e], d = dst[e];
    float norm = dinv[s] * dinv[d];
    atomicAdd(&agg2[(size_t)d * 32 + c], h2[(size_t)s * 32 + c] * norm);
}

// out = relu( relu(agg2 + b2) @ Wf + bf ) ; agg2 aliases out (in-place per row)
__global__ void k_final(const float* __restrict__ agg2, const float* __restrict__ b2,
                        const float* __restrict__ Wf, const float* __restrict__ bf,
                        float* __restrict__ out, int n) {
    int t = blockIdx.x * blockDim.x + threadIdx.x;
    if (t >= n * 32) return;
    int node = t >> 5, c2 = t & 31;
    const float* row = agg2 + (size_t)node * 32;
    float acc = bf[c2];
#pragma unroll
    for (int c = 0; c < 32; ++c) {
        float hv = fmaxf(row[c] + b2[c], 0.0f);
        acc = fmaf(hv, Wf[c * 32 + c2], acc);
    }
    out[t] = fmaxf(acc, 0.0f);
}

static inline size_t align_up(size_t x, size_t a) { return (x + a - 1) & ~(a - 1); }

extern "C" void kernel_launch(void* const* d_in, const int* in_sizes, int n_in,
                              void* d_out, int out_size, void* d_ws, size_t ws_size,
                              hipStream_t stream) {
    const int N = in_sizes[0] / 4;
    const int E = in_sizes[1] / 2;

    const float* x  = (const float*)d_in[0];
    const int*   ei = (const int*)d_in[1];
    const int*   src = ei;
    const int*   dst = ei + E;
    const float* W1 = (const float*)d_in[2];
    const float* b1 = (const float*)d_in[3];
    const float* W2 = (const float*)d_in[4];
    const float* b2 = (const float*)d_in[5];
    const float* Wf = (const float*)d_in[6];
    const float* bf = (const float*)d_in[7];
    float* out = (float*)d_out;

    char* w = (char*)d_ws;
    size_t off = 0;
    float* dinv = (float*)(w + off); off += align_up((size_t)N * 4, 256);
    float* h1   = (float*)(w + off); off += align_up((size_t)N * 64 * 4, 256);
    float* agg1 = (float*)(w + off); off += align_up((size_t)N * 64 * 4, 256);
    float* h2   = (float*)(w + off); off += align_up((size_t)N * 32 * 4, 256);
    float* agg2 = out;  // N*32 == out_size; overwritten in place by k_final

    const int B = 256;
    k_init_deg<<<(N + B - 1) / B, B, 0, stream>>>(dinv, N);
    k_count_deg<<<(E + B - 1) / B, B, 0, stream>>>(dst, dinv, E);
    k_dinv<<<(N + B - 1) / B, B, 0, stream>>>(dinv, N);

    k_lin1<<<((size_t)N * 64 + B - 1) / B, B, 0, stream>>>(x, W1, dinv, h1, agg1, N);
    k_scatter1<<<((size_t)E * 64 + B - 1) / B, B, 0, stream>>>(src, dst, dinv, h1, agg1, E);

    k_lin2<<<((size_t)N * 32 + B - 1) / B, B, 0, stream>>>(agg1, b1, W2, dinv, h2, agg2, N);
    k_scatter2<<<((size_t)E * 32 + B - 1) / B, B, 0, stream>>>(src, dst, dinv, h2, agg2, E);

    k_final<<<((size_t)N * 32 + B - 1) / B, B, 0, stream>>>(agg2, b2, Wf, bf, out, N);
}

// Round 2
// 717.003 us; speedup vs baseline: 1.0687x; 1.0687x over previous
//
#include <hip/hip_runtime.h>

// GCN encoder restructured via linearity:
//   conv1: S·(X W1) = (S·X) W1          -> scatter only 4 channels
//   conv2: S·(H W2)  with P = H W2 first -> scatter only 32 channels
// S = D^{-1/2}(A+I)D^{-1/2}, self-loop terms folded in as dinv^2 * row.

__global__ void k_init_deg(float* __restrict__ deg, int n) {
    int i = blockIdx.x * blockDim.x + threadIdx.x;
    if (i < n) deg[i] = 1.0f;  // self-loop
}

__global__ void k_count_deg(const int* __restrict__ dst, float* __restrict__ deg, int E) {
    int e = blockIdx.x * blockDim.x + threadIdx.x;
    if (e < E) atomicAdd(&deg[dst[e]], 1.0f);
}

// deg -> dinv, and init aggx with self-loop term x*dinv^2 (4 channels, float4)
__global__ void k_dinv_aggx(float* __restrict__ deg, const float* __restrict__ x,
                            float4* __restrict__ aggx, int n) {
    int i = blockIdx.x * blockDim.x + threadIdx.x;
    if (i >= n) return;
    float di = rsqrtf(deg[i]);  // deg >= 1 always
    deg[i] = di;                // now holds dinv
    float s = di * di;
    float4 xv = ((const float4*)x)[i];
    xv.x *= s; xv.y *= s; xv.z *= s; xv.w *= s;
    aggx[i] = xv;
}

// one thread per edge: 4 atomics into aggx[dst]
__global__ void k_scatter_x(const int* __restrict__ src, const int* __restrict__ dst,
                            const float* __restrict__ dinv, const float* __restrict__ x,
                            float* __restrict__ aggx, int E) {
    int e = blockIdx.x * blockDim.x + threadIdx.x;
    if (e >= E) return;
    int s = src[e], d = dst[e];
    float norm = dinv[s] * dinv[d];
    float4 xv = ((const float4*)x)[s];
    float* o = aggx + (size_t)d * 4;
    atomicAdd(o + 0, xv.x * norm);
    atomicAdd(o + 1, xv.y * norm);
    atomicAdd(o + 2, xv.z * norm);
    atomicAdd(o + 3, xv.w * norm);
}

// P[n][co] = sum_j relu(aggx[n]·W1[:,j] + b1[j]) * W2[j][co]
// also init aggP (=out) with self-loop term P*dinv^2
__global__ void k_dense1(const float4* __restrict__ aggx, const float* __restrict__ W1,
                         const float* __restrict__ b1, const float* __restrict__ W2,
                         const float* __restrict__ dinv, float* __restrict__ P,
                         float* __restrict__ aggP, int n) {
    int t = blockIdx.x * blockDim.x + threadIdx.x;
    if (t >= n * 32) return;
    int node = t >> 5, co = t & 31;
    float4 a = aggx[node];
    float acc = 0.0f;
#pragma unroll
    for (int j = 0; j < 64; ++j) {
        float v = fmaf(a.x, W1[j], fmaf(a.y, W1[64 + j],
                  fmaf(a.z, W1[128 + j], fmaf(a.w, W1[192 + j], b1[j]))));
        v = fmaxf(v, 0.0f);
        acc = fmaf(v, W2[j * 32 + co], acc);
    }
    P[t] = acc;
    float di = dinv[node];
    aggP[t] = acc * di * di;
}

// half-wave per edge, lane%32 = channel: 32-ch atomic scatter of P
__global__ void k_scatter_P(const int* __restrict__ src, const int* __restrict__ dst,
                            const float* __restrict__ dinv, const float* __restrict__ P,
                            float* __restrict__ aggP, int E) {
    unsigned t = blockIdx.x * (unsigned)blockDim.x + threadIdx.x;
    int e = (int)(t >> 5);
    int c = (int)(t & 31);
    if (e >= E) return;
    int s = src[e], d = dst[e];
    float norm = dinv[s] * dinv[d];
    atomicAdd(&aggP[(size_t)d * 32 + c], P[(size_t)s * 32 + c] * norm);
}

// out = relu( relu(aggP + b2) @ Wf + bf ); aggP aliases out (in-place per wave)
__global__ void k_final(const float* __restrict__ aggP, const float* __restrict__ b2,
                        const float* __restrict__ Wf, const float* __restrict__ bf,
                        float* __restrict__ out, int n) {
    int t = blockIdx.x * blockDim.x + threadIdx.x;
    if (t >= n * 32) return;
    int node = t >> 5, c2 = t & 31;
    const float* row = aggP + (size_t)node * 32;
    float acc = bf[c2];
#pragma unroll
    for (int c = 0; c < 32; ++c) {
        float hv = fmaxf(row[c] + b2[c], 0.0f);
        acc = fmaf(hv, Wf[c * 32 + c2], acc);
    }
    out[t] = fmaxf(acc, 0.0f);
}

static inline size_t align_up(size_t x, size_t a) { return (x + a - 1) & ~(a - 1); }

extern "C" void kernel_launch(void* const* d_in, const int* in_sizes, int n_in,
                              void* d_out, int out_size, void* d_ws, size_t ws_size,
                              hipStream_t stream) {
    const int N = in_sizes[0] / 4;
    const int E = in_sizes[1] / 2;

    const float* x  = (const float*)d_in[0];
    const int*   ei = (const int*)d_in[1];
    const int*   src = ei;
    const int*   dst = ei + E;
    const float* W1 = (const float*)d_in[2];
    const float* b1 = (const float*)d_in[3];
    const float* W2 = (const float*)d_in[4];
    const float* b2 = (const float*)d_in[5];
    const float* Wf = (const float*)d_in[6];
    const float* bf = (const float*)d_in[7];
    float* out = (float*)d_out;

    char* w = (char*)d_ws;
    size_t off = 0;
    float* dinv = (float*)(w + off); off += align_up((size_t)N * 4, 256);
    float* aggx = (float*)(w + off); off += align_up((size_t)N * 4 * 4, 256);
    float* P    = (float*)(w + off); off += align_up((size_t)N * 32 * 4, 256);
    float* aggP = out;  // N*32 == out_size; finalized in place by k_final

    const int B = 256;
    k_init_deg<<<(N + B - 1) / B, B, 0, stream>>>(dinv, N);
    k_count_deg<<<(E + B - 1) / B, B, 0, stream>>>(dst, dinv, E);
    k_dinv_aggx<<<(N + B - 1) / B, B, 0, stream>>>(dinv, x, (float4*)aggx, N);

    k_scatter_x<<<(E + B - 1) / B, B, 0, stream>>>(src, dst, dinv, x, aggx, E);

    k_dense1<<<((size_t)N * 32 + B - 1) / B, B, 0, stream>>>((const float4*)aggx, W1, b1, W2,
                                                             dinv, P, aggP, N);

    k_scatter_P<<<((size_t)E * 32 + B - 1) / B, B, 0, stream>>>(src, dst, dinv, P, aggP, E);

    k_final<<<((size_t)N * 32 + B - 1) / B, B, 0, stream>>>(aggP, b2, Wf, bf, out, N);
}

// Round 4
// 423.411 us; speedup vs baseline: 1.8097x; 1.6934x over previous
//
#include <hip/hip_runtime.h>

// GCN encoder, CSR-gather formulation (no fp32 atomics):
//   conv1: (S·X)W1  — aggregate 4-ch x first (gather), then dense
//   conv2: S·(H W2) — dense to 32-ch Q=P·dinv first, then gather + fused head
// CSR-by-dst built per call: int-atomic degree count -> scan -> slot fill.

#define SCAN_B 256

__global__ void k_zero(int* __restrict__ p, int n) {
    int i = blockIdx.x * blockDim.x + threadIdx.x;
    if (i < n) p[i] = 0;
}

__global__ void k_deg(const int* __restrict__ dst, int* __restrict__ deg, int E) {
    int e = blockIdx.x * blockDim.x + threadIdx.x;
    if (e < E) atomicAdd(&deg[dst[e]], 1);
}

// per-block exclusive scan of deg -> rowptr (local), block totals -> bsum
__global__ void k_scan1(const int* __restrict__ deg, int* __restrict__ rowptr,
                        int* __restrict__ bsum, int n) {
    __shared__ int tmp[SCAN_B];
    int i = blockIdx.x * SCAN_B + threadIdx.x;
    int v = (i < n) ? deg[i] : 0;
    tmp[threadIdx.x] = v;
    __syncthreads();
#pragma unroll
    for (int off = 1; off < SCAN_B; off <<= 1) {
        int t = (threadIdx.x >= (unsigned)off) ? tmp[threadIdx.x - off] : 0;
        __syncthreads();
        tmp[threadIdx.x] += t;
        __syncthreads();
    }
    if (i < n) rowptr[i] = tmp[threadIdx.x] - v;  // exclusive within block
    if (threadIdx.x == SCAN_B - 1) bsum[blockIdx.x] = tmp[SCAN_B - 1];
}

// single-block exclusive scan of block sums (nb <= 1024)
__global__ void k_scan2(int* __restrict__ bsum, int nb) {
    __shared__ int tmp[1024];
    int i = threadIdx.x;
    int v = (i < nb) ? bsum[i] : 0;
    tmp[i] = v;
    __syncthreads();
#pragma unroll
    for (int off = 1; off < 1024; off <<= 1) {
        int t = (i >= off) ? tmp[i - off] : 0;
        __syncthreads();
        tmp[i] += t;
        __syncthreads();
    }
    if (i < nb) bsum[i] = tmp[i] - v;  // exclusive
}

// finalize rowptr (+block offset), copy to fill cursor, compute dinv and xd=x*dinv
__global__ void k_scan3(int* __restrict__ rowptr, const int* __restrict__ bsum,
                        int* __restrict__ cnt, const int* __restrict__ deg,
                        float* __restrict__ dinv, const float4* __restrict__ x,
                        float4* __restrict__ xd, int n) {
    int i = blockIdx.x * blockDim.x + threadIdx.x;
    if (i >= n) return;
    int rp = rowptr[i] + bsum[i >> 8];
    rowptr[i] = rp;
    cnt[i] = rp;
    float di = rsqrtf((float)(deg[i] + 1));  // +1 self-loop
    dinv[i] = di;
    float4 xv = x[i];
    xv.x *= di; xv.y *= di; xv.z *= di; xv.w *= di;
    xd[i] = xv;
}

// bucket edges by dst: adj[slot] = src
__global__ void k_fill(const int* __restrict__ src, const int* __restrict__ dst,
                       int* __restrict__ cnt, int* __restrict__ adj, int E) {
    int e = blockIdx.x * blockDim.x + threadIdx.x;
    if (e >= E) return;
    int pos = atomicAdd(&cnt[dst[e]], 1);
    adj[pos] = src[e];
}

// aggx[d] = dinv[d] * ( xd[d] + sum_{s in in(d)} xd[s] )   (4 channels)
__global__ void k_gather_x(const int* __restrict__ rowptr, const int* __restrict__ deg,
                           const int* __restrict__ adj, const float* __restrict__ dinv,
                           const float4* __restrict__ xd, float4* __restrict__ aggx, int n) {
    int i = blockIdx.x * blockDim.x + threadIdx.x;
    if (i >= n) return;
    float4 acc = xd[i];  // self-loop term (xd already has dinv[i] factor)
    int beg = rowptr[i], c = deg[i];
    for (int k = 0; k < c; ++k) {
        int s = adj[beg + k];
        float4 v = xd[s];
        acc.x += v.x; acc.y += v.y; acc.z += v.z; acc.w += v.w;
    }
    float di = dinv[i];
    acc.x *= di; acc.y *= di; acc.z *= di; acc.w *= di;
    aggx[i] = acc;
}

// Q[n][co] = dinv[n] * sum_j relu(aggx[n]·W1[:,j] + b1[j]) * W2[j][co]
__global__ void k_dense1(const float4* __restrict__ aggx, const float* __restrict__ W1,
                         const float* __restrict__ b1, const float* __restrict__ W2,
                         const float* __restrict__ dinv, float* __restrict__ Q, int n) {
    int t = blockIdx.x * blockDim.x + threadIdx.x;
    if (t >= n * 32) return;
    int node = t >> 5, co = t & 31;
    float4 a = aggx[node];
    float acc = 0.0f;
#pragma unroll
    for (int j = 0; j < 64; ++j) {
        float v = fmaf(a.x, W1[j], fmaf(a.y, W1[64 + j],
                  fmaf(a.z, W1[128 + j], fmaf(a.w, W1[192 + j], b1[j]))));
        v = fmaxf(v, 0.0f);
        acc = fmaf(v, W2[j * 32 + co], acc);
    }
    Q[t] = acc * dinv[node];
}

// Fused: layer-2 gather + relu(+b2) + @Wf + bf + relu -> out.
// One half-wave (32 lanes = 32 channels) per node. NEEDS N*32 threads.
__global__ void k_gather_final(const int* __restrict__ rowptr, const int* __restrict__ deg,
                               const int* __restrict__ adj, const float* __restrict__ dinv,
                               const float* __restrict__ Q, const float* __restrict__ b2,
                               const float* __restrict__ Wf, const float* __restrict__ bf,
                               float* __restrict__ out, int n) {
    int node = blockIdx.x * (blockDim.x >> 5) + (threadIdx.x >> 5);
    int lane = threadIdx.x & 31;
    bool valid = node < n;
    int nd = valid ? node : 0;
    float acc = Q[(size_t)nd * 32 + lane];  // self-loop (Q has dinv[s] factor)
    int beg = rowptr[nd];
    int c = valid ? deg[nd] : 0;
    for (int k = 0; k < c; ++k) {
        int s = adj[beg + k];
        acc += Q[(size_t)s * 32 + lane];
    }
    float h = fmaxf(fmaf(acc, dinv[nd], b2[lane]), 0.0f);  // relu(conv2 + b2)
    float o = bf[lane];
#pragma unroll
    for (int cc = 0; cc < 32; ++cc) {
        o = fmaf(__shfl(h, cc, 32), Wf[cc * 32 + lane], o);
    }
    if (valid) out[(size_t)node * 32 + lane] = fmaxf(o, 0.0f);
}

static inline size_t align_up(size_t x, size_t a) { return (x + a - 1) & ~(a - 1); }

extern "C" void kernel_launch(void* const* d_in, const int* in_sizes, int n_in,
                              void* d_out, int out_size, void* d_ws, size_t ws_size,
                              hipStream_t stream) {
    const int N = in_sizes[0] / 4;
    const int E = in_sizes[1] / 2;

    const float* x  = (const float*)d_in[0];
    const int*   ei = (const int*)d_in[1];
    const int*   src = ei;
    const int*   dst = ei + E;
    const float* W1 = (const float*)d_in[2];
    const float* b1 = (const float*)d_in[3];
    const float* W2 = (const float*)d_in[4];
    const float* b2 = (const float*)d_in[5];
    const float* Wf = (const float*)d_in[6];
    const float* bf = (const float*)d_in[7];
    float* out = (float*)d_out;

    char* w = (char*)d_ws;
    size_t off = 0;
    int*   deg    = (int*)(w + off);    off += align_up((size_t)N * 4, 256);
    int*   rowptr = (int*)(w + off);    off += align_up((size_t)N * 4, 256);
    int*   cnt    = (int*)(w + off);    off += align_up((size_t)N * 4, 256);
    int*   bsum   = (int*)(w + off);    off += align_up(1024 * 4, 256);
    int*   adj    = (int*)(w + off);    off += align_up((size_t)E * 4, 256);
    float* dinv   = (float*)(w + off);  off += align_up((size_t)N * 4, 256);
    float* xd     = (float*)(w + off);  off += align_up((size_t)N * 16, 256);
    float* aggx   = (float*)(w + off);  off += align_up((size_t)N * 16, 256);
    float* Q      = (float*)(w + off);  off += align_up((size_t)N * 32 * 4, 256);

    const int B = 256;
    const int nb = (N + SCAN_B - 1) / SCAN_B;  // 391 for N=100k; k_scan2 handles <=1024

    k_zero<<<(N + B - 1) / B, B, 0, stream>>>(deg, N);
    k_deg<<<(E + B - 1) / B, B, 0, stream>>>(dst, deg, E);
    k_scan1<<<nb, SCAN_B, 0, stream>>>(deg, rowptr, bsum, N);
    k_scan2<<<1, 1024, 0, stream>>>(bsum, nb);
    k_scan3<<<(N + B - 1) / B, B, 0, stream>>>(rowptr, bsum, cnt, deg, dinv,
                                               (const float4*)x, (float4*)xd, N);
    k_fill<<<(E + B - 1) / B, B, 0, stream>>>(src, dst, cnt, adj, E);

    k_gather_x<<<(N + B - 1) / B, B, 0, stream>>>(rowptr, deg, adj, dinv,
                                                  (const float4*)xd, (float4*)aggx, N);
    k_dense1<<<((size_t)N * 32 + B - 1) / B, B, 0, stream>>>((const float4*)aggx, W1, b1, W2,
                                                             dinv, Q, N);
    // 32 threads (half-wave) per node -> N*32 threads total
    k_gather_final<<<((size_t)N * 32 + B - 1) / B, B, 0, stream>>>(rowptr, deg, adj, dinv, Q,
                                                                   b2, Wf, bf, out, N);
}

// Round 5
// 267.546 us; speedup vs baseline: 2.8640x; 1.5826x over previous
//
#include <hip/hip_runtime.h>

// GCN encoder, CSR-gather formulation (no fp32 atomics):
//   conv1: (S·X)W1  — aggregate 4-ch x (parallel gather) fused with dense W1/W2
//   conv2: S·(H W2) — gather 32-ch Q rows, fused with final linear head
// CSR-by-dst: atomic degree count captures per-edge rank -> scan -> atomic-free fill.

#define SCAN_B 256

// degree count; atomic's return value = edge's slot within its dst row
__global__ void k_deg_rank(const int* __restrict__ dst, int* __restrict__ deg,
                           int* __restrict__ rank, int E) {
    int e = blockIdx.x * blockDim.x + threadIdx.x;
    if (e < E) rank[e] = atomicAdd(&deg[dst[e]], 1);
}

// per-block exclusive scan of deg -> rowptr (local), block totals -> bsum
__global__ void k_scan1(const int* __restrict__ deg, int* __restrict__ rowptr,
                        int* __restrict__ bsum, int n) {
    __shared__ int tmp[SCAN_B];
    int i = blockIdx.x * SCAN_B + threadIdx.x;
    int v = (i < n) ? deg[i] : 0;
    tmp[threadIdx.x] = v;
    __syncthreads();
#pragma unroll
    for (int off = 1; off < SCAN_B; off <<= 1) {
        int t = (threadIdx.x >= (unsigned)off) ? tmp[threadIdx.x - off] : 0;
        __syncthreads();
        tmp[threadIdx.x] += t;
        __syncthreads();
    }
    if (i < n) rowptr[i] = tmp[threadIdx.x] - v;  // exclusive within block
    if (threadIdx.x == SCAN_B - 1) bsum[blockIdx.x] = tmp[SCAN_B - 1];
}

// single-block exclusive scan of block sums (nb <= 1024)
__global__ void k_scan2(int* __restrict__ bsum, int nb) {
    __shared__ int tmp[1024];
    int i = threadIdx.x;
    int v = (i < nb) ? bsum[i] : 0;
    tmp[i] = v;
    __syncthreads();
#pragma unroll
    for (int off = 1; off < 1024; off <<= 1) {
        int t = (i >= off) ? tmp[i - off] : 0;
        __syncthreads();
        tmp[i] += t;
        __syncthreads();
    }
    if (i < nb) bsum[i] = tmp[i] - v;  // exclusive
}

// finalize rowptr (+block offset), compute dinv and xd = x*dinv
__global__ void k_scan3(int* __restrict__ rowptr, const int* __restrict__ bsum,
                        const int* __restrict__ deg, float* __restrict__ dinv,
                        const float4* __restrict__ x, float4* __restrict__ xd, int n) {
    int i = blockIdx.x * blockDim.x + threadIdx.x;
    if (i >= n) return;
    rowptr[i] += bsum[i >> 8];
    float di = rsqrtf((float)(deg[i] + 1));  // +1 self-loop
    dinv[i] = di;
    float4 xv = x[i];
    xv.x *= di; xv.y *= di; xv.z *= di; xv.w *= di;
    xd[i] = xv;
}

// atomic-free bucket fill: adj[rowptr[dst] + rank] = src
__global__ void k_fill(const int* __restrict__ src, const int* __restrict__ dst,
                       const int* __restrict__ rowptr, const int* __restrict__ rank,
                       int* __restrict__ adj, int E) {
    int e = blockIdx.x * blockDim.x + threadIdx.x;
    if (e >= E) return;
    adj[rowptr[dst[e]] + rank[e]] = src[e];
}

// Fused conv1: half-wave per node. Lanes cooperatively gather xd rows (4 ch),
// butterfly-reduce, then each lane computes output channel of relu(·W1+b1)·W2·dinv.
__global__ void k_conv1(const int* __restrict__ rowptr, const int* __restrict__ deg,
                        const int* __restrict__ adj, const float* __restrict__ dinv,
                        const float4* __restrict__ xd,
                        const float* __restrict__ W1, const float* __restrict__ b1,
                        const float* __restrict__ W2, float* __restrict__ Q, int n) {
    int node = blockIdx.x * (blockDim.x >> 5) + (threadIdx.x >> 5);
    int lane = threadIdx.x & 31;
    bool valid = node < n;
    int nd = valid ? node : 0;
    int beg = rowptr[nd];
    int c = valid ? deg[nd] : 0;

    float ax = 0.f, ay = 0.f, az = 0.f, aw = 0.f;
    int k = lane;
    for (; k + 32 < c; k += 64) {  // 2 loads in flight per lane
        int s0 = adj[beg + k], s1 = adj[beg + k + 32];
        float4 v0 = xd[s0], v1 = xd[s1];
        ax += v0.x + v1.x; ay += v0.y + v1.y; az += v0.z + v1.z; aw += v0.w + v1.w;
    }
    if (k < c) {
        float4 v = xd[adj[beg + k]];
        ax += v.x; ay += v.y; az += v.z; aw += v.w;
    }
#pragma unroll
    for (int m = 16; m >= 1; m >>= 1) {
        ax += __shfl_xor(ax, m, 32);
        ay += __shfl_xor(ay, m, 32);
        az += __shfl_xor(az, m, 32);
        aw += __shfl_xor(aw, m, 32);
    }
    float4 self = xd[nd];  // broadcast load
    float di = dinv[nd];
    ax = (ax + self.x) * di; ay = (ay + self.y) * di;
    az = (az + self.z) * di; aw = (aw + self.w) * di;

    float r = 0.0f;
#pragma unroll
    for (int j = 0; j < 64; ++j) {
        float v = fmaf(ax, W1[j], fmaf(ay, W1[64 + j],
                  fmaf(az, W1[128 + j], fmaf(aw, W1[192 + j], b1[j]))));
        v = fmaxf(v, 0.0f);
        r = fmaf(v, W2[j * 32 + lane], r);
    }
    if (valid) Q[(size_t)nd * 32 + lane] = r * di;  // Q = (H W2)·dinv
}

// Fused: layer-2 gather + relu(+b2) + @Wf + bf + relu -> out.
// Half-wave per node; neighbor loop 4x unrolled for MLP. NEEDS N*32 threads.
__global__ void k_gather_final(const int* __restrict__ rowptr, const int* __restrict__ deg,
                               const int* __restrict__ adj, const float* __restrict__ dinv,
                               const float* __restrict__ Q, const float* __restrict__ b2,
                               const float* __restrict__ Wf, const float* __restrict__ bf,
                               float* __restrict__ out, int n) {
    int node = blockIdx.x * (blockDim.x >> 5) + (threadIdx.x >> 5);
    int lane = threadIdx.x & 31;
    bool valid = node < n;
    int nd = valid ? node : 0;
    float acc = Q[(size_t)nd * 32 + lane];  // self-loop (Q carries dinv[s])
    int beg = rowptr[nd];
    int c = valid ? deg[nd] : 0;
    int k = 0;
    for (; k + 4 <= c; k += 4) {
        int s0 = adj[beg + k], s1 = adj[beg + k + 1];
        int s2 = adj[beg + k + 2], s3 = adj[beg + k + 3];
        float q0 = Q[(size_t)s0 * 32 + lane];
        float q1 = Q[(size_t)s1 * 32 + lane];
        float q2 = Q[(size_t)s2 * 32 + lane];
        float q3 = Q[(size_t)s3 * 32 + lane];
        acc += (q0 + q1) + (q2 + q3);
    }
    for (; k < c; ++k) acc += Q[(size_t)adj[beg + k] * 32 + lane];

    float h = fmaxf(fmaf(acc, dinv[nd], b2[lane]), 0.0f);  // relu(conv2 + b2)
    float o = bf[lane];
#pragma unroll
    for (int cc = 0; cc < 32; ++cc) {
        o = fmaf(__shfl(h, cc, 32), Wf[cc * 32 + lane], o);
    }
    if (valid) out[(size_t)node * 32 + lane] = fmaxf(o, 0.0f);
}

static inline size_t align_up(size_t x, size_t a) { return (x + a - 1) & ~(a - 1); }

extern "C" void kernel_launch(void* const* d_in, const int* in_sizes, int n_in,
                              void* d_out, int out_size, void* d_ws, size_t ws_size,
                              hipStream_t stream) {
    const int N = in_sizes[0] / 4;
    const int E = in_sizes[1] / 2;

    const float* x  = (const float*)d_in[0];
    const int*   ei = (const int*)d_in[1];
    const int*   src = ei;
    const int*   dst = ei + E;
    const float* W1 = (const float*)d_in[2];
    const float* b1 = (const float*)d_in[3];
    const float* W2 = (const float*)d_in[4];
    const float* b2 = (const float*)d_in[5];
    const float* Wf = (const float*)d_in[6];
    const float* bf = (const float*)d_in[7];
    float* out = (float*)d_out;

    char* w = (char*)d_ws;
    size_t off = 0;
    int*   deg    = (int*)(w + off);    off += align_up((size_t)N * 4, 256);
    int*   rowptr = (int*)(w + off);    off += align_up((size_t)N * 4, 256);
    int*   rank   = (int*)(w + off);    off += align_up((size_t)E * 4, 256);
    int*   bsum   = (int*)(w + off);    off += align_up(1024 * 4, 256);
    int*   adj    = (int*)(w + off);    off += align_up((size_t)E * 4, 256);
    float* dinv   = (float*)(w + off);  off += align_up((size_t)N * 4, 256);
    float* xd     = (float*)(w + off);  off += align_up((size_t)N * 16, 256);
    float* Q      = (float*)(w + off);  off += align_up((size_t)N * 32 * 4, 256);

    const int B = 256;
    const int nb = (N + SCAN_B - 1) / SCAN_B;  // 391 for N=100k; k_scan2 handles <=1024

    hipMemsetAsync(deg, 0, (size_t)N * 4, stream);
    k_deg_rank<<<(E + B - 1) / B, B, 0, stream>>>(dst, deg, rank, E);
    k_scan1<<<nb, SCAN_B, 0, stream>>>(deg, rowptr, bsum, N);
    k_scan2<<<1, 1024, 0, stream>>>(bsum, nb);
    k_scan3<<<(N + B - 1) / B, B, 0, stream>>>(rowptr, bsum, deg, dinv,
                                               (const float4*)x, (float4*)xd, N);
    k_fill<<<(E + B - 1) / B, B, 0, stream>>>(src, dst, rowptr, rank, adj, E);

    k_conv1<<<((size_t)N * 32 + B - 1) / B, B, 0, stream>>>(rowptr, deg, adj, dinv,
                                                            (const float4*)xd,
                                                            W1, b1, W2, Q, N);
    k_gather_final<<<((size_t)N * 32 + B - 1) / B, B, 0, stream>>>(rowptr, deg, adj, dinv, Q,
                                                                   b2, Wf, bf, out, N);
}